// Round 10
// baseline (344.278 us; speedup 1.0000x reference)
//
#include <hip/hip_runtime.h>
#include <hip/hip_bf16.h>
#include <math.h>

#define NEG_SLOPE 0.2f

typedef short short8 __attribute__((ext_vector_type(8)));
typedef float floatx4 __attribute__((ext_vector_type(4)));

static __device__ __forceinline__ float bf2f(unsigned short u) {
  return __uint_as_float(((unsigned int)u) << 16);
}
static __device__ __forceinline__ unsigned short f2bf(float f) {
  unsigned int u = __float_as_uint(f);
  u = (u + 0x7fffu + ((u >> 16) & 1u)) >> 16;  // RNE
  return (unsigned short)u;
}
static __device__ __forceinline__ unsigned int pack2(float a, float b) {
  __hip_bfloat162 h = __float22bfloat162_rn(make_float2(a, b));  // v_cvt_pk_bf16_f32
  unsigned int u;
  __builtin_memcpy(&u, &h, 4);
  return u;
}

// ---------- A: prep — W1->bf16^T, deg=1, ei->ushort, scan flags=0 ----------
__global__ void prep_kernel(const float* __restrict__ W1, unsigned short* __restrict__ W1t,
                            int* __restrict__ deg, const int* __restrict__ ei,
                            unsigned short* __restrict__ src16, unsigned short* __restrict__ dst16,
                            int* __restrict__ flags, int nb, int N, int E) {
  int i = blockIdx.x * 256 + threadIdx.x;
  if (i < 32768) {
    int k = i >> 6, c = i & 63;
    W1t[c * 512 + k] = f2bf(W1[i]);
  }
  int j = i - 32768;
  if (j >= 0 && j < N) deg[j] = 1;  // self-loop
  int e = i - 32768 - N;
  if (e >= 0 && e < E) {
    src16[e] = (unsigned short)ei[e];
    dst16[e] = (unsigned short)ei[E + e];
  }
  int f = i - 32768 - N - E;
  if (f >= 0 && f < nb) flags[f] = 0;
}

// ---------- B: fused [XCD-sliced hist] + [GEMM1 via MFMA] ----------
// blockIdx < HB: histogram (reads ei directly, atomics to deg).
// blockIdx >= HB: 64-row MFMA gemm tile. Hist hides under BW-bound gemm.
__global__ __launch_bounds__(256) void hist_gemm1(const int* __restrict__ ei,
                                                  int* __restrict__ deg,
                                                  const float* __restrict__ A,
                                                  const unsigned short* __restrict__ W1t,
                                                  const float* __restrict__ att_src,
                                                  const float* __restrict__ att_dst,
                                                  unsigned short* __restrict__ xlb,
                                                  float* __restrict__ a_src,
                                                  float* __restrict__ a_dst,
                                                  int M, int E, int N, int ipc, int HB) {
  __shared__ unsigned short As[64 * 72];  // pad 72: 2-way bank alias = free
  __shared__ unsigned short Bs[64 * 72];
  if (blockIdx.x < (unsigned)HB) {
    int slice = blockIdx.x & 7;
    int chunk = blockIdx.x >> 3;
    int lo = (int)(((long long)slice * N) >> 3);
    int hi = (int)(((long long)(slice + 1) * N) >> 3);
    int beg = chunk * ipc;
    int end = min(beg + ipc, E);
    for (int i = beg + threadIdx.x; i < end; i += 256) {
      int d = ei[E + i];
      if (d >= lo && d < hi) atomicAdd(&deg[d], 1);
    }
    return;
  }
  int tid = threadIdx.x;
  int w = tid >> 6, lane = tid & 63;
  int q = lane >> 4, cl = lane & 15;
  int row0 = (blockIdx.x - HB) << 6;

  floatx4 acc[4] = {};
  int sr = tid >> 2;            // staging row/col 0..63
  int skq = (tid & 3) << 4;     // k offset 0,16,32,48
  int arow = row0 + sr;
  const float* Aptr = A + (size_t)arow * 512 + skq;
  const unsigned short* Bptr = W1t + sr * 512 + skq;
  unsigned short* AsW = As + sr * 72 + skq;
  unsigned short* BsW = Bs + sr * 72 + skq;

  for (int k0 = 0; k0 < 512; k0 += 64) {
    float4 f0 = make_float4(0.f, 0.f, 0.f, 0.f), f1 = f0, f2 = f0, f3 = f0;
    if (arow < M) {
      f0 = *(const float4*)(Aptr + k0);
      f1 = *(const float4*)(Aptr + k0 + 4);
      f2 = *(const float4*)(Aptr + k0 + 8);
      f3 = *(const float4*)(Aptr + k0 + 12);
    }
    uint4 b0 = *(const uint4*)(Bptr + k0);
    uint4 b1 = *(const uint4*)(Bptr + k0 + 8);
    __syncthreads();
    uint4 a0, a1;
    a0.x = pack2(f0.x, f0.y); a0.y = pack2(f0.z, f0.w);
    a0.z = pack2(f1.x, f1.y); a0.w = pack2(f1.z, f1.w);
    a1.x = pack2(f2.x, f2.y); a1.y = pack2(f2.z, f2.w);
    a1.z = pack2(f3.x, f3.y); a1.w = pack2(f3.z, f3.w);
    *(uint4*)(AsW) = a0;
    *(uint4*)(AsW + 8) = a1;
    *(uint4*)(BsW) = b0;
    *(uint4*)(BsW + 8) = b1;
    __syncthreads();
#pragma unroll
    for (int kk = 0; kk < 2; ++kk) {
      short8 af = *(const short8*)(As + (w * 16 + cl) * 72 + kk * 32 + q * 8);
#pragma unroll
      for (int t = 0; t < 4; ++t) {
        short8 bf = *(const short8*)(Bs + (t * 16 + cl) * 72 + kk * 32 + q * 8);
        acc[t] = __builtin_amdgcn_mfma_f32_16x16x32_bf16(af, bf, acc[t], 0, 0, 0);
      }
    }
  }

  // epilogue: C/D layout col = cl (within tile), row = q*4 + reg
  float asv[4], adv[4];
#pragma unroll
  for (int t = 0; t < 4; ++t) {
    asv[t] = att_src[t * 16 + cl];
    adv[t] = att_dst[t * 16 + cl];
  }
#pragma unroll
  for (int reg = 0; reg < 4; ++reg) {
    int r = row0 + w * 16 + q * 4 + reg;
    bool ok = r < M;
#pragma unroll
    for (int t = 0; t < 4; ++t) {
      float v = acc[t][reg];
      if (ok) xlb[(size_t)r * 64 + t * 16 + cl] = f2bf(v);
      float ps = v * asv[t];
      float pd = v * adv[t];
      ps += __shfl_xor(ps, 1); pd += __shfl_xor(pd, 1);
      ps += __shfl_xor(ps, 2); pd += __shfl_xor(pd, 2);
      ps += __shfl_xor(ps, 4); pd += __shfl_xor(pd, 4);
      if (ok && (cl & 7) == 0) {
        int h = t * 2 + (cl >> 3);
        a_src[r * 8 + h] = ps;
        a_dst[r * 8 + h] = pd;
      }
    }
  }
}

// ---------- C: single-dispatch chained scan (decoupled lookback) ----------
// 512 elems/block; flags: 0=none, 1=aggregate ready, 2=inclusive prefix ready.
__global__ __launch_bounds__(256) void scan_chained(const int* __restrict__ deg,
                                                    int* __restrict__ rowptr,
                                                    int* __restrict__ cursor,
                                                    int* __restrict__ block_agg,
                                                    int* __restrict__ block_pfx,
                                                    int* __restrict__ flags,
                                                    int N, int nb) {
  __shared__ int wavesum[4];
  __shared__ int base_sh;
  int bid = blockIdx.x;
  int base = bid * 512;
  int tid = threadIdx.x;
  int lane = tid & 63, wv = tid >> 6;
  int i0 = base + tid * 2;
  int d0 = (i0 < N) ? deg[i0] : 0;
  int d1 = (i0 + 1 < N) ? deg[i0 + 1] : 0;
  int s = d0 + d1;
  int v = s;
#pragma unroll
  for (int off = 1; off < 64; off <<= 1) {
    int t = __shfl_up(v, off, 64);
    if (lane >= off) v += t;
  }
  if (lane == 63) wavesum[wv] = v;
  __syncthreads();
  int S = wavesum[0] + wavesum[1] + wavesum[2] + wavesum[3];
  if (tid == 0) {
    if (bid == 0) {
      block_pfx[0] = S;
      __hip_atomic_store(&flags[0], 2, __ATOMIC_RELEASE, __HIP_MEMORY_SCOPE_AGENT);
      base_sh = 0;
      if (nb == 1) rowptr[N] = S;
    } else {
      block_agg[bid] = S;
      __hip_atomic_store(&flags[bid], 1, __ATOMIC_RELEASE, __HIP_MEMORY_SCOPE_AGENT);
      int run = 0, j = bid - 1;
      while (true) {
        int f = __hip_atomic_load(&flags[j], __ATOMIC_ACQUIRE, __HIP_MEMORY_SCOPE_AGENT);
        if (f == 2) { run += block_pfx[j]; break; }
        if (f == 1) { run += block_agg[j]; --j; }
      }
      block_pfx[bid] = run + S;
      __hip_atomic_store(&flags[bid], 2, __ATOMIC_RELEASE, __HIP_MEMORY_SCOPE_AGENT);
      base_sh = run;
      if (bid == nb - 1) rowptr[N] = run + S;
    }
  }
  __syncthreads();
  int woff = base_sh;
  for (int w = 0; w < wv; ++w) woff += wavesum[w];
  int excl = v - s + woff;
  if (i0 < N) { rowptr[i0] = excl; cursor[i0] = excl; }
  if (i0 + 1 < N) { rowptr[i0 + 1] = excl + d0; cursor[i0 + 1] = excl + d0; }
}

// ---------- D: XCD-sliced scatter (ushort) ----------
__global__ __launch_bounds__(256) void scatter_sliced(const unsigned short* __restrict__ src16,
                                                      const unsigned short* __restrict__ dst16,
                                                      int* __restrict__ cursor,
                                                      unsigned short* __restrict__ srcs,
                                                      int E, int N, int ipc) {
  int slice = blockIdx.x & 7;
  int chunk = blockIdx.x >> 3;
  int lo = (int)(((long long)slice * N) >> 3);
  int hi = (int)(((long long)(slice + 1) * N) >> 3);
  int total = E + N;
  int beg = chunk * ipc;
  int end = min(beg + ipc, total);
  for (int i = beg + threadIdx.x; i < end; i += 256) {
    int d = (i < E) ? (int)dst16[i] : (i - E);
    if (d >= lo && d < hi) {
      int s = (i < E) ? (int)src16[i] : d;
      int pos = atomicAdd(&cursor[d], 1);
      srcs[pos] = (unsigned short)s;
    }
  }
}

// ---------- E: layer-1 aggregation, one wave/node, scalarized indices ----------
__global__ __launch_bounds__(256) void agg1_csr(const int* __restrict__ rowptr,
                                                const unsigned short* __restrict__ srcs,
                                                const float* __restrict__ a_src,
                                                const float* __restrict__ a_dst,
                                                const unsigned short* __restrict__ xlb,
                                                float* __restrict__ agg1, int N) {
  int wave = (blockIdx.x * blockDim.x + threadIdx.x) >> 6;
  int lane = threadIdx.x & 63;
  if (wave >= N) return;
  int h = lane >> 3;
  int beg = rowptr[wave], end = rowptr[wave + 1];
  float ad = a_dst[wave * 8 + h];
  float den = 0.f, acc = 0.f;
  int p = beg;
  for (; p + 8 <= end; p += 8) {
    int myv = (int)srcs[p + (lane & 7)];  // coalesced; lanes 0..7 hold the 8 edges
    int s0 = __builtin_amdgcn_readlane(myv, 0);
    int s1 = __builtin_amdgcn_readlane(myv, 1);
    int s2 = __builtin_amdgcn_readlane(myv, 2);
    int s3 = __builtin_amdgcn_readlane(myv, 3);
    int s4 = __builtin_amdgcn_readlane(myv, 4);
    int s5 = __builtin_amdgcn_readlane(myv, 5);
    int s6 = __builtin_amdgcn_readlane(myv, 6);
    int s7 = __builtin_amdgcn_readlane(myv, 7);
    float a0 = a_src[s0 * 8 + h], a1 = a_src[s1 * 8 + h];
    float a2 = a_src[s2 * 8 + h], a3 = a_src[s3 * 8 + h];
    float a4 = a_src[s4 * 8 + h], a5 = a_src[s5 * 8 + h];
    float a6 = a_src[s6 * 8 + h], a7 = a_src[s7 * 8 + h];
    float x0 = bf2f(xlb[(size_t)s0 * 64 + lane]);
    float x1 = bf2f(xlb[(size_t)s1 * 64 + lane]);
    float x2 = bf2f(xlb[(size_t)s2 * 64 + lane]);
    float x3 = bf2f(xlb[(size_t)s3 * 64 + lane]);
    float x4 = bf2f(xlb[(size_t)s4 * 64 + lane]);
    float x5 = bf2f(xlb[(size_t)s5 * 64 + lane]);
    float x6 = bf2f(xlb[(size_t)s6 * 64 + lane]);
    float x7 = bf2f(xlb[(size_t)s7 * 64 + lane]);
    a0 += ad; a1 += ad; a2 += ad; a3 += ad;
    a4 += ad; a5 += ad; a6 += ad; a7 += ad;
    a0 = a0 >= 0.f ? a0 : NEG_SLOPE * a0;
    a1 = a1 >= 0.f ? a1 : NEG_SLOPE * a1;
    a2 = a2 >= 0.f ? a2 : NEG_SLOPE * a2;
    a3 = a3 >= 0.f ? a3 : NEG_SLOPE * a3;
    a4 = a4 >= 0.f ? a4 : NEG_SLOPE * a4;
    a5 = a5 >= 0.f ? a5 : NEG_SLOPE * a5;
    a6 = a6 >= 0.f ? a6 : NEG_SLOPE * a6;
    a7 = a7 >= 0.f ? a7 : NEG_SLOPE * a7;
    float w0 = __expf(a0), w1 = __expf(a1), w2 = __expf(a2), w3 = __expf(a3);
    float w4 = __expf(a4), w5 = __expf(a5), w6 = __expf(a6), w7 = __expf(a7);
    den += ((w0 + w1) + (w2 + w3)) + ((w4 + w5) + (w6 + w7));
    acc += w0 * x0 + w1 * x1 + w2 * x2 + w3 * x3;
    acc += w4 * x4 + w5 * x5 + w6 * x6 + w7 * x7;
  }
  for (; p < end; ++p) {
    int s = __builtin_amdgcn_readfirstlane((int)srcs[p]);
    float a = a_src[s * 8 + h] + ad;
    a = a >= 0.f ? a : NEG_SLOPE * a;
    float w = __expf(a);
    den += w;
    acc += w * bf2f(xlb[(size_t)s * 64 + lane]);
  }
  agg1[(size_t)wave * 64 + lane] = acc / (den + 1e-16f);
}

// ---------- F: layer-2 GEMM (bias1 fused) + attention coefs ----------
__global__ __launch_bounds__(256) void gemm2_prep(const float* __restrict__ agg1,
                                                  const float* __restrict__ bias1,
                                                  const float* __restrict__ W2,
                                                  const float* __restrict__ att_src2,
                                                  const float* __restrict__ att_dst2,
                                                  float* __restrict__ xl2,
                                                  float* __restrict__ a_src2,
                                                  float* __restrict__ a_dst2, int N) {
  __shared__ float hs[16 * 68];
  int tid = threadIdx.x;
  int n0 = blockIdx.x << 4;
  {
    int node = tid >> 4;
    int off = (tid & 15) << 2;
    int nn = n0 + node;
    float4 v = make_float4(0.f, 0.f, 0.f, 0.f);
    if (nn < N) {
      v = *(const float4*)(agg1 + (size_t)nn * 64 + off);
      float4 b = *(const float4*)(bias1 + off);
      v.x += b.x; v.y += b.y; v.z += b.z; v.w += b.w;
    }
    *(float4*)(hs + node * 68 + off) = v;
  }
  __syncthreads();
  int t = tid >> 4, c = tid & 15;
  int n = n0 + t;
  if (n >= N) return;
  float sum = 0.f;
#pragma unroll
  for (int k = 0; k < 64; ++k) sum += hs[t * 68 + k] * W2[k * 16 + c];
  xl2[(size_t)n * 16 + c] = sum;
  float ps = sum * att_src2[c];
  float pd = sum * att_dst2[c];
#pragma unroll
  for (int w = 8; w >= 1; w >>= 1) {
    ps += __shfl_xor(ps, w, 16);
    pd += __shfl_xor(pd, w, 16);
  }
  if (c == 0) {
    a_src2[n] = ps;
    a_dst2[n] = pd;
  }
}

// ---------- G: layer-2 aggregation + bias2 + ELU + log_softmax ----------
__global__ __launch_bounds__(256) void agg2_fin(const int* __restrict__ rowptr,
                                                const unsigned short* __restrict__ srcs,
                                                const float* __restrict__ a_src2,
                                                const float* __restrict__ a_dst2,
                                                const float* __restrict__ xl2,
                                                const float* __restrict__ bias2,
                                                float* __restrict__ out, int N) {
  int t = blockIdx.x * blockDim.x + threadIdx.x;
  int node = t >> 4;
  int c = t & 15;
  if (node >= N) return;
  int beg = rowptr[node], end = rowptr[node + 1];
  float ad = a_dst2[node];
  float den = 0.f, acc = 0.f;
  int p = beg;
  for (; p + 8 <= end; p += 8) {
    int s0 = srcs[p], s1 = srcs[p + 1], s2 = srcs[p + 2], s3 = srcs[p + 3];
    int s4 = srcs[p + 4], s5 = srcs[p + 5], s6 = srcs[p + 6], s7 = srcs[p + 7];
    float a0 = a_src2[s0], a1 = a_src2[s1], a2 = a_src2[s2], a3 = a_src2[s3];
    float a4 = a_src2[s4], a5 = a_src2[s5], a6 = a_src2[s6], a7 = a_src2[s7];
    float x0 = xl2[(size_t)s0 * 16 + c], x1 = xl2[(size_t)s1 * 16 + c];
    float x2 = xl2[(size_t)s2 * 16 + c], x3 = xl2[(size_t)s3 * 16 + c];
    float x4 = xl2[(size_t)s4 * 16 + c], x5 = xl2[(size_t)s5 * 16 + c];
    float x6 = xl2[(size_t)s6 * 16 + c], x7 = xl2[(size_t)s7 * 16 + c];
    a0 += ad; a1 += ad; a2 += ad; a3 += ad;
    a4 += ad; a5 += ad; a6 += ad; a7 += ad;
    a0 = a0 >= 0.f ? a0 : NEG_SLOPE * a0;
    a1 = a1 >= 0.f ? a1 : NEG_SLOPE * a1;
    a2 = a2 >= 0.f ? a2 : NEG_SLOPE * a2;
    a3 = a3 >= 0.f ? a3 : NEG_SLOPE * a3;
    a4 = a4 >= 0.f ? a4 : NEG_SLOPE * a4;
    a5 = a5 >= 0.f ? a5 : NEG_SLOPE * a5;
    a6 = a6 >= 0.f ? a6 : NEG_SLOPE * a6;
    a7 = a7 >= 0.f ? a7 : NEG_SLOPE * a7;
    float w0 = __expf(a0), w1 = __expf(a1), w2 = __expf(a2), w3 = __expf(a3);
    float w4 = __expf(a4), w5 = __expf(a5), w6 = __expf(a6), w7 = __expf(a7);
    den += ((w0 + w1) + (w2 + w3)) + ((w4 + w5) + (w6 + w7));
    acc += w0 * x0 + w1 * x1 + w2 * x2 + w3 * x3;
    acc += w4 * x4 + w5 * x5 + w6 * x6 + w7 * x7;
  }
  for (; p < end; ++p) {
    int s = srcs[p];
    float a = a_src2[s] + ad;
    a = a >= 0.f ? a : NEG_SLOPE * a;
    float w = __expf(a);
    den += w;
    acc += w * xl2[(size_t)s * 16 + c];
  }
  float o = acc / (den + 1e-16f) + bias2[c];
  o = o > 0.f ? o : expm1f(o);  // ELU alpha=1
  float mx = o;
#pragma unroll
  for (int w = 8; w >= 1; w >>= 1) mx = fmaxf(mx, __shfl_xor(mx, w, 16));
  float e = __expf(o - mx);
  float ssum = e;
#pragma unroll
  for (int w = 8; w >= 1; w >>= 1) ssum += __shfl_xor(ssum, w, 16);
  out[(size_t)node * 16 + c] = o - mx - logf(ssum);
}

extern "C" void kernel_launch(void* const* d_in, const int* in_sizes, int n_in,
                              void* d_out, int out_size, void* d_ws, size_t ws_size,
                              hipStream_t stream) {
  const float* x        = (const float*)d_in[0];
  const int*   ei       = (const int*)d_in[1];
  const float* W1       = (const float*)d_in[2];
  const float* att_src1 = (const float*)d_in[3];
  const float* att_dst1 = (const float*)d_in[4];
  const float* bias1    = (const float*)d_in[5];
  const float* W2       = (const float*)d_in[6];
  const float* att_src2 = (const float*)d_in[7];
  const float* att_dst2 = (const float*)d_in[8];
  const float* bias2    = (const float*)d_in[9];
  float* out = (float*)d_out;

  int N = in_sizes[0] / 512;
  int E = in_sizes[1] / 2;
  int nb = (N + 511) / 512;

  char* wsp = (char*)d_ws;
  auto alloc = [&](size_t bytes) {
    char* p = wsp;
    wsp += (bytes + 255) & ~(size_t)255;
    return p;
  };
  unsigned short* xlb   = (unsigned short*)alloc((size_t)N * 64 * 2);
  unsigned short* W1t   = (unsigned short*)alloc((size_t)512 * 64 * 2);
  float* a_src1 = (float*)alloc((size_t)N * 8 * 4);
  float* a_dst1 = (float*)alloc((size_t)N * 8 * 4);
  float* agg1   = (float*)alloc((size_t)N * 64 * 4);
  float* xl2    = (float*)alloc((size_t)N * 16 * 4);
  float* a_src2 = (float*)alloc((size_t)N * 4);
  float* a_dst2 = (float*)alloc((size_t)N * 4);
  int* deg      = (int*)alloc((size_t)N * 4);
  int* rowptr   = (int*)alloc((size_t)(N + 1) * 4);
  int* cursor   = (int*)alloc((size_t)N * 4);
  int* block_agg = (int*)alloc((size_t)nb * 4);
  int* block_pfx = (int*)alloc((size_t)nb * 4);
  int* flags     = (int*)alloc((size_t)nb * 4);
  unsigned short* src16 = (unsigned short*)alloc((size_t)E * 2);
  unsigned short* dst16 = (unsigned short*)alloc((size_t)E * 2);
  unsigned short* srcs  = (unsigned short*)alloc((size_t)(E + N) * 2);

  const int NCHUNK = 256;
  const int HB = NCHUNK * 8;
  int ipc_h = (E + NCHUNK - 1) / NCHUNK;
  int ipc_s = (E + N + NCHUNK - 1) / NCHUNK;
  int GB = (N + 63) / 64;

  // A
  prep_kernel<<<(32768 + N + E + nb + 255) / 256, 256, 0, stream>>>(
      W1, W1t, deg, ei, src16, dst16, flags, nb, N, E);
  // B: hist (blocks [0,HB)) overlapped with gemm1 (blocks [HB, HB+GB))
  hist_gemm1<<<HB + GB, 256, 0, stream>>>(ei, deg, x, W1t, att_src1, att_dst1,
                                          xlb, a_src1, a_dst1, N, E, N, ipc_h, HB);
  // C: single-dispatch chained scan
  scan_chained<<<nb, 256, 0, stream>>>(deg, rowptr, cursor, block_agg, block_pfx, flags, N, nb);
  // D
  scatter_sliced<<<NCHUNK * 8, 256, 0, stream>>>(src16, dst16, cursor, srcs, E, N, ipc_s);
  // E
  agg1_csr<<<((size_t)N * 64 + 255) / 256, 256, 0, stream>>>(rowptr, srcs, a_src1, a_dst1,
                                                             xlb, agg1, N);
  // F
  gemm2_prep<<<(N + 15) / 16, 256, 0, stream>>>(agg1, bias1, W2, att_src2, att_dst2,
                                                xl2, a_src2, a_dst2, N);
  // G
  agg2_fin<<<((size_t)N * 16 + 255) / 256, 256, 0, stream>>>(rowptr, srcs, a_src2, a_dst2,
                                                             xl2, bias2, out, N);
}